// Round 1
// baseline (1016.337 us; speedup 1.0000x reference)
//
#include <hip/hip_runtime.h>

// HybridEulerIntegrator: a[t,b] scan, MLP 2->64->1 with tanh, a += C*dk^3.
// Parallel over B (16384 elements), serial over T (2048).
// 8 lanes per element, 8 hidden units per lane; butterfly shfl_xor reduce.
// 131072 threads = 2048 waves = 2 waves/SIMD across 256 CUs.

#define SEQ_T  2048
#define NB     16384
#define NH     64
#define C_GAIN 0.001f

__device__ __forceinline__ float fast_tanh(float p) {
    // tanh(p) = 1 - 2/(1 + e^{2p});  e^{2p} = exp2(p * 2*log2(e))
    // Large +p: exp2 -> inf -> rcp -> 0 -> +1.  Large -p: exp2 -> 0 -> -1.
    float e = __builtin_amdgcn_exp2f(p * 2.8853900817779268f);
    float r = __builtin_amdgcn_rcpf(e + 1.0f);
    return fmaf(-2.0f, r, 1.0f);
}

struct LaneW {
    float w1x[8], w1a[8], b1v[8], w2v[8];
    float b2s;
};

__device__ __forceinline__ float do_step(float a, float xv, const LaneW& W) {
    float acc = 0.0f;
#pragma unroll
    for (int u = 0; u < 8; ++u) {
        float p = fmaf(xv, W.w1x[u], fmaf(a, W.w1a[u], W.b1v[u]));
        acc = fmaf(fast_tanh(p), W.w2v[u], acc);
    }
    // reduce across the 8 hidden-chunk lanes (bits 3..5 of lane id)
    acc += __shfl_xor(acc, 8, 64);
    acc += __shfl_xor(acc, 16, 64);
    acc += __shfl_xor(acc, 32, 64);
    float dk  = acc + W.b2s;
    float dk3 = dk * dk * dk;           // M = 3.0 (odd integer -> plain cube)
    return fmaf(C_GAIN, dk3, a);
}

__global__ __launch_bounds__(256) void integ_kernel(
        const float* __restrict__ x,  const float* __restrict__ a0,
        const float* __restrict__ W1, const float* __restrict__ b1,
        const float* __restrict__ W2, const float* __restrict__ b2,
        float* __restrict__ out) {
    const int lane = threadIdx.x & 63;
    const int wv   = threadIdx.x >> 6;     // wave in block (0..3)
    const int e    = lane & 7;             // element slot   (0..7)
    const int h    = lane >> 3;            // hidden chunk   (0..7)
    const int b    = blockIdx.x * 32 + wv * 8 + e;
    const int j0   = h * 8;

    LaneW W;
#pragma unroll
    for (int u = 0; u < 8; ++u) {
        W.w1x[u] = W1[j0 + u];        // W1 row 0: weight on x
        W.w1a[u] = W1[NH + j0 + u];   // W1 row 1: weight on a
        W.b1v[u] = b1[j0 + u];
        W.w2v[u] = W2[j0 + u];
    }
    W.b2s = b2[0];

    float a = a0[b];
    const float* xp = x + b;

    // software prefetch, distance 4, two register banks of 4 steps each
    float xA[4], xB[4];
#pragma unroll
    for (int i = 0; i < 4; ++i) xA[i] = xp[i * NB];

    for (int t8 = 0; t8 < SEQ_T; t8 += 8) {
        // prefetch bank B (steps t8+4 .. t8+7)
#pragma unroll
        for (int i = 0; i < 4; ++i) xB[i] = xp[(t8 + 4 + i) * NB];

#pragma unroll
        for (int k = 0; k < 4; ++k) {
            a = do_step(a, xA[k], W);
            if (h == 0) out[(t8 + k) * NB + b] = a;
        }

        // prefetch bank A (steps t8+8 .. t8+11), skip on last iteration
        if (t8 + 8 < SEQ_T) {
#pragma unroll
            for (int i = 0; i < 4; ++i) xA[i] = xp[(t8 + 8 + i) * NB];
        }

#pragma unroll
        for (int k = 0; k < 4; ++k) {
            a = do_step(a, xB[k], W);
            if (h == 0) out[(t8 + 4 + k) * NB + b] = a;
        }
    }
}

extern "C" void kernel_launch(void* const* d_in, const int* in_sizes, int n_in,
                              void* d_out, int out_size, void* d_ws, size_t ws_size,
                              hipStream_t stream) {
    const float* x  = (const float*)d_in[0];
    const float* a0 = (const float*)d_in[1];
    const float* W1 = (const float*)d_in[2];
    const float* b1 = (const float*)d_in[3];
    const float* W2 = (const float*)d_in[4];
    const float* b2 = (const float*)d_in[5];
    float* out = (float*)d_out;

    // 8 lanes/element * 16384 elements = 131072 threads; 256/block -> 512 blocks
    dim3 grid(NB / 32);
    dim3 block(256);
    hipLaunchKernelGGL(integ_kernel, grid, block, 0, stream,
                       x, a0, W1, b1, W2, b2, out);
}

// Round 2
// 931.681 us; speedup vs baseline: 1.0909x; 1.0909x over previous
//
#include <hip/hip_runtime.h>

// HybridEulerIntegrator R1: 16 lanes/element, 4 hidden units/lane.
// 16384 elem * 16 lanes = 262144 threads = 4096 waves = 4 waves/SIMD.
// Per-unit body strength-reduced to fma,fma,exp2,add,rcp,fma (4 reg + 2 trans):
//   - 2*log2(e) folded into W1/b1 (exp2(K*p) == e^{2p})
//   - tanh affine folded out: sum_j w2_j tanh_j = (sum w2) - 2*sum w2_j r_j
//     with r_j = 1/(1+e^{2p_j});  b2'' = b2 + sum_j w2_j  (one-time butterfly)

#define SEQ_T  2048
#define NB     16384
#define NH     64
#define C_GAIN 0.001f
#define K2LOG2E 2.8853900817779268f   // 2/ln(2)

struct LaneW {
    float w1x[4], w1a[4], b1v[4], w2v[4];
    float b2pp;   // b2 + sum_j w2_j  (full 64-unit sum)
};

__device__ __forceinline__ float do_step(float a, float xv, const LaneW& W) {
    float R = 0.0f;
#pragma unroll
    for (int u = 0; u < 4; ++u) {
        float p = fmaf(xv, W.w1x[u], fmaf(a, W.w1a[u], W.b1v[u]));  // = 2p/ln2
        float e = __builtin_amdgcn_exp2f(p);                         // = e^{2p}
        float r = __builtin_amdgcn_rcpf(e + 1.0f);
        R = fmaf(W.w2v[u], r, R);
    }
    // butterfly over the 16 hidden-chunk lanes (bits 0..3 of lane id)
    R += __shfl_xor(R, 1, 64);
    R += __shfl_xor(R, 2, 64);
    R += __shfl_xor(R, 4, 64);
    R += __shfl_xor(R, 8, 64);
    float dk = fmaf(-2.0f, R, W.b2pp);
    return fmaf(dk * dk * C_GAIN, dk, a);   // a + C*dk^3
}

__global__ __launch_bounds__(256, 4) void integ_kernel(
        const float* __restrict__ x,  const float* __restrict__ a0,
        const float* __restrict__ W1, const float* __restrict__ b1,
        const float* __restrict__ W2, const float* __restrict__ b2,
        float* __restrict__ out) {
    const int lane = threadIdx.x & 63;
    const int wv   = threadIdx.x >> 6;     // wave in block (0..3)
    const int e    = lane >> 4;            // element slot   (0..3)
    const int h    = lane & 15;            // hidden chunk   (0..15)
    const int b    = blockIdx.x * 16 + wv * 4 + e;
    const int j0   = h * 4;

    LaneW W;
    float sw2 = 0.0f;
#pragma unroll
    for (int u = 0; u < 4; ++u) {
        W.w1x[u] = W1[j0 + u] * K2LOG2E;        // W1 row 0: weight on x
        W.w1a[u] = W1[NH + j0 + u] * K2LOG2E;   // W1 row 1: weight on a
        W.b1v[u] = b1[j0 + u] * K2LOG2E;
        W.w2v[u] = W2[j0 + u];
        sw2 += W.w2v[u];
    }
    sw2 += __shfl_xor(sw2, 1, 64);
    sw2 += __shfl_xor(sw2, 2, 64);
    sw2 += __shfl_xor(sw2, 4, 64);
    sw2 += __shfl_xor(sw2, 8, 64);
    W.b2pp = b2[0] + sw2;

    float a = a0[b];
    const float* xp = x + b;

    // software prefetch, distance 4, two register banks of 4 steps each
    float xA[4], xB[4];
#pragma unroll
    for (int i = 0; i < 4; ++i) xA[i] = xp[i * NB];

    for (int t8 = 0; t8 < SEQ_T; t8 += 8) {
        // prefetch bank B (steps t8+4 .. t8+7)
#pragma unroll
        for (int i = 0; i < 4; ++i) xB[i] = xp[(t8 + 4 + i) * NB];

#pragma unroll
        for (int k = 0; k < 4; ++k) {
            a = do_step(a, xA[k], W);
            if (h == 0) out[(t8 + k) * NB + b] = a;
        }

        // prefetch bank A (steps t8+8 .. t8+11), skip on last iteration
        if (t8 + 8 < SEQ_T) {
#pragma unroll
            for (int i = 0; i < 4; ++i) xA[i] = xp[(t8 + 8 + i) * NB];
        }

#pragma unroll
        for (int k = 0; k < 4; ++k) {
            a = do_step(a, xB[k], W);
            if (h == 0) out[(t8 + 4 + k) * NB + b] = a;
        }
    }
}

extern "C" void kernel_launch(void* const* d_in, const int* in_sizes, int n_in,
                              void* d_out, int out_size, void* d_ws, size_t ws_size,
                              hipStream_t stream) {
    const float* x  = (const float*)d_in[0];
    const float* a0 = (const float*)d_in[1];
    const float* W1 = (const float*)d_in[2];
    const float* b1 = (const float*)d_in[3];
    const float* W2 = (const float*)d_in[4];
    const float* b2 = (const float*)d_in[5];
    float* out = (float*)d_out;

    // 16 lanes/element * 16384 elements = 262144 threads; 256/block -> 1024 blocks
    dim3 grid(NB / 16);
    dim3 block(256);
    hipLaunchKernelGGL(integ_kernel, grid, block, 0, stream,
                       x, a0, W1, b1, W2, b2, out);
}

// Round 3
// 925.477 us; speedup vs baseline: 1.0982x; 1.0067x over previous
//
#include <hip/hip_runtime.h>

// HybridEulerIntegrator R2: 16 lanes/element, 4 hidden units/lane,
// 4-way rcp amortization: sum_{j in 4} w_j/(1+e_j) = N/D computed with
// ONE v_rcp_f32 (trans ~16cyc) instead of four.
//   D = f1 f2 f3 f4,  N = sum_j w_j prod_{k!=j} f_k   (pairwise tree)
// exp2 arg clamped at 30 so no f can be inf (saturated unit -> w*2^-30 ~ 0,
// matching true sigmoid saturation; D <= 2^120 stays finite).
// 16384 elem * 16 lanes = 262144 threads = 4096 waves = 4 waves/SIMD.

#define SEQ_T  2048
#define NB     16384
#define NH     64
#define C_GAIN 0.001f
#define K2LOG2E 2.8853900817779268f   // 2/ln(2)
#define QCLAMP  30.0f                 // e = 2^q <= 2^30; 4-product <= 2^120

struct LaneW {
    float w1x[4], w1a[4], b1v[4], w2v[4];
    float b2pp;   // b2 + sum_j w2_j  (full 64-unit sum)
};

__device__ __forceinline__ float do_step(float a, float xv, const LaneW& W) {
    float q0 = fmaf(xv, W.w1x[0], fmaf(a, W.w1a[0], W.b1v[0]));
    float q1 = fmaf(xv, W.w1x[1], fmaf(a, W.w1a[1], W.b1v[1]));
    float q2 = fmaf(xv, W.w1x[2], fmaf(a, W.w1a[2], W.b1v[2]));
    float q3 = fmaf(xv, W.w1x[3], fmaf(a, W.w1a[3], W.b1v[3]));
    q0 = fminf(q0, QCLAMP); q1 = fminf(q1, QCLAMP);
    q2 = fminf(q2, QCLAMP); q3 = fminf(q3, QCLAMP);
    float f0 = __builtin_amdgcn_exp2f(q0) + 1.0f;
    float f1 = __builtin_amdgcn_exp2f(q1) + 1.0f;
    float f2 = __builtin_amdgcn_exp2f(q2) + 1.0f;
    float f3 = __builtin_amdgcn_exp2f(q3) + 1.0f;
    float g01 = f0 * f1, g23 = f2 * f3;
    float n01 = W.w2v[0] * f1; n01 = fmaf(W.w2v[1], f0, n01);
    float n23 = W.w2v[2] * f3; n23 = fmaf(W.w2v[3], f2, n23);
    float D = g01 * g23;
    float N = n01 * g23;  N = fmaf(n23, g01, N);
    float R = N * __builtin_amdgcn_rcpf(D);   // = sum_j w2_j / (1 + e^{2p_j})

    // butterfly over the 16 hidden-chunk lanes (bits 0..3 of lane id)
    R += __shfl_xor(R, 1, 64);
    R += __shfl_xor(R, 2, 64);
    R += __shfl_xor(R, 4, 64);
    R += __shfl_xor(R, 8, 64);
    float dk = fmaf(-2.0f, R, W.b2pp);
    return fmaf(dk * dk * C_GAIN, dk, a);   // a + C*dk^3
}

__global__ __launch_bounds__(256, 4) void integ_kernel(
        const float* __restrict__ x,  const float* __restrict__ a0,
        const float* __restrict__ W1, const float* __restrict__ b1,
        const float* __restrict__ W2, const float* __restrict__ b2,
        float* __restrict__ out) {
    const int lane = threadIdx.x & 63;
    const int wv   = threadIdx.x >> 6;     // wave in block (0..3)
    const int e    = lane >> 4;            // element slot   (0..3)
    const int h    = lane & 15;            // hidden chunk   (0..15)
    const int b    = blockIdx.x * 16 + wv * 4 + e;
    const int j0   = h * 4;

    LaneW W;
    float sw2 = 0.0f;
#pragma unroll
    for (int u = 0; u < 4; ++u) {
        W.w1x[u] = W1[j0 + u] * K2LOG2E;        // W1 row 0: weight on x
        W.w1a[u] = W1[NH + j0 + u] * K2LOG2E;   // W1 row 1: weight on a
        W.b1v[u] = b1[j0 + u] * K2LOG2E;
        W.w2v[u] = W2[j0 + u];
        sw2 += W.w2v[u];
    }
    sw2 += __shfl_xor(sw2, 1, 64);
    sw2 += __shfl_xor(sw2, 2, 64);
    sw2 += __shfl_xor(sw2, 4, 64);
    sw2 += __shfl_xor(sw2, 8, 64);
    W.b2pp = b2[0] + sw2;

    float a = a0[b];
    const float* xp = x + b;

    // software prefetch, distance 4, two register banks of 4 steps each
    float xA[4], xB[4];
#pragma unroll
    for (int i = 0; i < 4; ++i) xA[i] = xp[i * NB];

    for (int t8 = 0; t8 < SEQ_T; t8 += 8) {
        // prefetch bank B (steps t8+4 .. t8+7)
#pragma unroll
        for (int i = 0; i < 4; ++i) xB[i] = xp[(t8 + 4 + i) * NB];

#pragma unroll
        for (int k = 0; k < 4; ++k) {
            a = do_step(a, xA[k], W);
            if (h == 0) out[(t8 + k) * NB + b] = a;
        }

        // prefetch bank A (steps t8+8 .. t8+11), skip on last iteration
        if (t8 + 8 < SEQ_T) {
#pragma unroll
            for (int i = 0; i < 4; ++i) xA[i] = xp[(t8 + 8 + i) * NB];
        }

#pragma unroll
        for (int k = 0; k < 4; ++k) {
            a = do_step(a, xB[k], W);
            if (h == 0) out[(t8 + 4 + k) * NB + b] = a;
        }
    }
}

extern "C" void kernel_launch(void* const* d_in, const int* in_sizes, int n_in,
                              void* d_out, int out_size, void* d_ws, size_t ws_size,
                              hipStream_t stream) {
    const float* x  = (const float*)d_in[0];
    const float* a0 = (const float*)d_in[1];
    const float* W1 = (const float*)d_in[2];
    const float* b1 = (const float*)d_in[3];
    const float* W2 = (const float*)d_in[4];
    const float* b2 = (const float*)d_in[5];
    float* out = (float*)d_out;

    dim3 grid(NB / 16);
    dim3 block(256);
    hipLaunchKernelGGL(integ_kernel, grid, block, 0, stream,
                       x, a0, W1, b1, W2, b2, out);
}